// Round 1
// baseline (405.831 us; speedup 1.0000x reference)
//
#include <hip/hip_runtime.h>

#define D_FEAT 64

__global__ void deg_kernel(const int* __restrict__ src, const int* __restrict__ dst,
                           float* __restrict__ outdeg, float* __restrict__ indeg,
                           int n_edges) {
    int i = blockIdx.x * blockDim.x + threadIdx.x;
    int stride = gridDim.x * blockDim.x;
    for (; i < n_edges; i += stride) {
        atomicAdd(&outdeg[src[i]], 1.0f);
        atomicAdd(&indeg[dst[i]], 1.0f);
    }
}

__global__ void rsqrt_deg_kernel(float* __restrict__ outdeg, float* __restrict__ indeg,
                                 int n_nodes) {
    int i = blockIdx.x * blockDim.x + threadIdx.x;
    if (i < n_nodes) {
        float o = outdeg[i];
        float d = indeg[i];
        outdeg[i] = rsqrtf(fmaxf(o, 1.0f));
        indeg[i]  = rsqrtf(fmaxf(d, 1.0f));
    }
}

// One 64-lane wave per edge; lane j handles feature j.
__global__ void scatter_kernel(const float* __restrict__ u_f,
                               const int* __restrict__ src,
                               const int* __restrict__ dst,
                               const float* __restrict__ outdeg_rs,
                               float* __restrict__ out,
                               int n_edges) {
    const int lane = threadIdx.x & 63;
    const int edges_per_block = blockDim.x >> 6;          // 4 for 256 threads
    long long e = (long long)blockIdx.x * edges_per_block + (threadIdx.x >> 6);
    if (e >= n_edges) return;
    const int s = src[e];
    const int d = dst[e];
    const float scale = outdeg_rs[s];
    const float v = u_f[(long long)s * D_FEAT + lane] * scale;
    atomicAdd(&out[(long long)d * D_FEAT + lane], v);
}

// float4-vectorized row scale by indeg^-0.5
__global__ void scale_kernel(float* __restrict__ out,
                             const float* __restrict__ indeg_rs,
                             int n_nodes) {
    int tid = blockIdx.x * blockDim.x + threadIdx.x;     // one per float4
    int n_vec = n_nodes * (D_FEAT / 4);
    if (tid < n_vec) {
        int node = tid / (D_FEAT / 4);
        float s = indeg_rs[node];
        float4* p = reinterpret_cast<float4*>(out) + tid;
        float4 v = *p;
        v.x *= s; v.y *= s; v.z *= s; v.w *= s;
        *p = v;
    }
}

extern "C" void kernel_launch(void* const* d_in, const int* in_sizes, int n_in,
                              void* d_out, int out_size, void* d_ws, size_t ws_size,
                              hipStream_t stream) {
    const float* u_f = (const float*)d_in[0];
    const int*   src = (const int*)d_in[1];
    const int*   dst = (const int*)d_in[2];
    float* out = (float*)d_out;

    const int n_nodes = in_sizes[0] / D_FEAT;
    const int n_edges = in_sizes[1];

    float* outdeg = (float*)d_ws;
    float* indeg  = outdeg + n_nodes;

    // Zero degree counters + output accumulator (ws/out are poisoned, not zeroed).
    hipMemsetAsync(d_ws, 0, (size_t)2 * n_nodes * sizeof(float), stream);
    hipMemsetAsync(d_out, 0, (size_t)out_size * sizeof(float), stream);

    deg_kernel<<<2048, 256, 0, stream>>>(src, dst, outdeg, indeg, n_edges);

    rsqrt_deg_kernel<<<(n_nodes + 255) / 256, 256, 0, stream>>>(outdeg, indeg, n_nodes);

    const int epb = 256 / 64;                      // edges per block
    const int blocks = (n_edges + epb - 1) / epb;  // 300000 blocks
    scatter_kernel<<<blocks, 256, 0, stream>>>(u_f, src, dst, outdeg, out, n_edges);

    const int n_vec = n_nodes * (D_FEAT / 4);
    scale_kernel<<<(n_vec + 255) / 256, 256, 0, stream>>>(out, indeg, n_nodes);
}

// Round 2
// 278.083 us; speedup vs baseline: 1.4594x; 1.4594x over previous
//
#include <hip/hip_runtime.h>

#define D_FEAT 64
#define SCAN_CHUNK 1024   // elements scanned per block in scan1

// --- Pass 1: degree histograms (int atomics on 100K counters) ---
__global__ void hist_kernel(const int* __restrict__ src, const int* __restrict__ dst,
                            int* __restrict__ out_cnt, int* __restrict__ in_cnt,
                            int n_edges) {
    int i = blockIdx.x * blockDim.x + threadIdx.x;
    int stride = gridDim.x * blockDim.x;
    for (; i < n_edges; i += stride) {
        atomicAdd(&out_cnt[src[i]], 1);
        atomicAdd(&in_cnt[dst[i]], 1);
    }
}

// --- Pass 2: per-node scales ---
__global__ void scale_kernel(const int* __restrict__ out_cnt, const int* __restrict__ in_cnt,
                             float* __restrict__ oscale, float* __restrict__ iscale,
                             int n_nodes) {
    int i = blockIdx.x * blockDim.x + threadIdx.x;
    if (i < n_nodes) {
        oscale[i] = rsqrtf((float)max(out_cnt[i], 1));
        iscale[i] = rsqrtf((float)max(in_cnt[i], 1));
    }
}

// --- Pass 3a: per-chunk exclusive scan of in_cnt (chunk = 1024 elems, block = 256 thr × 4) ---
__global__ void scan1_kernel(const int* __restrict__ in_cnt,
                             int* __restrict__ local_off, int* __restrict__ chunk_tot,
                             int n_nodes) {
    __shared__ int part[256];
    const int t = threadIdx.x;
    const int base = blockIdx.x * SCAN_CHUNK + t * 4;
    int v0 = 0, v1 = 0, v2 = 0, v3 = 0;
    if (base + 0 < n_nodes) v0 = in_cnt[base + 0];
    if (base + 1 < n_nodes) v1 = in_cnt[base + 1];
    if (base + 2 < n_nodes) v2 = in_cnt[base + 2];
    if (base + 3 < n_nodes) v3 = in_cnt[base + 3];
    const int mysum = v0 + v1 + v2 + v3;
    part[t] = mysum;
    __syncthreads();
    // Hillis-Steele inclusive scan over 256 partials
    for (int off = 1; off < 256; off <<= 1) {
        int x = (t >= off) ? part[t - off] : 0;
        __syncthreads();
        part[t] += x;
        __syncthreads();
    }
    const int excl = part[t] - mysum;   // exclusive prefix of this thread's 4 elems
    if (base + 0 < n_nodes) local_off[base + 0] = excl;
    if (base + 1 < n_nodes) local_off[base + 1] = excl + v0;
    if (base + 2 < n_nodes) local_off[base + 2] = excl + v0 + v1;
    if (base + 3 < n_nodes) local_off[base + 3] = excl + v0 + v1 + v2;
    if (t == 255) chunk_tot[blockIdx.x] = part[255];
}

// --- Pass 3b: exclusive scan of chunk totals (single block; n_chunks <= 256) ---
__global__ void scan2_kernel(int* __restrict__ chunk_tot, int* __restrict__ chunk_off,
                             int n_chunks) {
    __shared__ int part[256];
    const int t = threadIdx.x;
    int v = (t < n_chunks) ? chunk_tot[t] : 0;
    part[t] = v;
    __syncthreads();
    for (int off = 1; off < 256; off <<= 1) {
        int x = (t >= off) ? part[t - off] : 0;
        __syncthreads();
        part[t] += x;
        __syncthreads();
    }
    if (t < n_chunks) chunk_off[t] = part[t] - v;
}

// --- Pass 4: bin edges by dst (counting sort) ---
__global__ void bin_kernel(const int* __restrict__ src, const int* __restrict__ dst,
                           const int* __restrict__ local_off, const int* __restrict__ chunk_off,
                           int* __restrict__ cursor, int* __restrict__ sorted_src,
                           int n_edges) {
    int i = blockIdx.x * blockDim.x + threadIdx.x;
    int stride = gridDim.x * blockDim.x;
    for (; i < n_edges; i += stride) {
        const int d = dst[i];
        const int pos = local_off[d] + chunk_off[d >> 10] + atomicAdd(&cursor[d], 1);
        sorted_src[pos] = src[i];
    }
}

// --- Pass 5: segmented gather-reduce. One 64-lane wave per dst node, lane = feature. ---
__global__ void agg_kernel(const float* __restrict__ u_f,
                           const int* __restrict__ sorted_src,
                           const int* __restrict__ local_off, const int* __restrict__ chunk_off,
                           const int* __restrict__ in_cnt,
                           const float* __restrict__ oscale, const float* __restrict__ iscale,
                           float* __restrict__ out, int n_nodes) {
    const int lane = threadIdx.x & 63;
    const int node = blockIdx.x * (blockDim.x >> 6) + (threadIdx.x >> 6);
    if (node >= n_nodes) return;
    const int start = local_off[node] + chunk_off[node >> 10];
    const int cnt = in_cnt[node];
    float acc = 0.0f;
    int k = 0;
    for (; k + 1 < cnt; k += 2) {           // 2-deep to overlap dependent load chains
        const int s0 = sorted_src[start + k];
        const int s1 = sorted_src[start + k + 1];
        const float w0 = oscale[s0];
        const float w1 = oscale[s1];
        acc += u_f[(size_t)s0 * D_FEAT + lane] * w0;
        acc += u_f[(size_t)s1 * D_FEAT + lane] * w1;
    }
    if (k < cnt) {
        const int s0 = sorted_src[start + k];
        acc += u_f[(size_t)s0 * D_FEAT + lane] * oscale[s0];
    }
    out[(size_t)node * D_FEAT + lane] = acc * iscale[node];
}

extern "C" void kernel_launch(void* const* d_in, const int* in_sizes, int n_in,
                              void* d_out, int out_size, void* d_ws, size_t ws_size,
                              hipStream_t stream) {
    const float* u_f = (const float*)d_in[0];
    const int*   src = (const int*)d_in[1];
    const int*   dst = (const int*)d_in[2];
    float* out = (float*)d_out;

    const int n_nodes = in_sizes[0] / D_FEAT;
    const int n_edges = in_sizes[1];
    const int n_chunks = (n_nodes + SCAN_CHUNK - 1) / SCAN_CHUNK;   // 98 for 100K

    // Workspace layout (ints/floats, 4B each):
    // [out_cnt n][in_cnt n][cursor n] | [oscale n][iscale n][local_off n][chunk stuff n] | [sorted_src m]
    int* out_cnt   = (int*)d_ws;
    int* in_cnt    = out_cnt + n_nodes;
    int* cursor    = out_cnt + 2 * n_nodes;
    float* oscale  = (float*)(out_cnt + 3 * n_nodes);
    float* iscale  = (float*)(out_cnt + 4 * n_nodes);
    int* local_off = out_cnt + 5 * n_nodes;
    int* chunk_tot = out_cnt + 6 * n_nodes;            // n_chunks entries
    int* chunk_off = chunk_tot + n_chunks;             // n_chunks entries
    int* sorted_src = out_cnt + 7 * n_nodes;           // n_edges entries

    // Zero the three counter arrays (contiguous).
    hipMemsetAsync(d_ws, 0, (size_t)3 * n_nodes * sizeof(int), stream);

    hist_kernel<<<2048, 256, 0, stream>>>(src, dst, out_cnt, in_cnt, n_edges);
    scale_kernel<<<(n_nodes + 255) / 256, 256, 0, stream>>>(out_cnt, in_cnt, oscale, iscale, n_nodes);
    scan1_kernel<<<n_chunks, 256, 0, stream>>>(in_cnt, local_off, chunk_tot, n_nodes);
    scan2_kernel<<<1, 256, 0, stream>>>(chunk_tot, chunk_off, n_chunks);
    bin_kernel<<<2048, 256, 0, stream>>>(src, dst, local_off, chunk_off, cursor, sorted_src, n_edges);

    const int waves_per_block = 256 / 64;
    const int agg_blocks = (n_nodes + waves_per_block - 1) / waves_per_block;
    agg_kernel<<<agg_blocks, 256, 0, stream>>>(u_f, sorted_src, local_off, chunk_off,
                                               in_cnt, oscale, iscale, out, n_nodes);
}